// Round 1
// baseline (131.434 us; speedup 1.0000x reference)
//
#include <hip/hip_runtime.h>
#include <math.h>

#define NTAP 65
#define LEN 524288
#define LSUB 131072   // LEN/4
#define BATCH 16

struct Filt { float h[4][NTAP]; };   // 1040 bytes, passed by value (kernarg)

// ---------------- Analysis: sub[b,k,i] = sum_n h[k][n] * x[b, 4i-32+n] ----------------
__global__ __launch_bounds__(256) void pqmf_analysis(const float* __restrict__ x,
                                                     float* __restrict__ sub,
                                                     Filt F) {
    int idx = blockIdx.x * blockDim.x + threadIdx.x;   // BATCH*LSUB threads
    int i = idx & (LSUB - 1);
    int b = idx >> 17;
    const float* xb = x + (size_t)b * LEN;
    float w[NTAP];
    int base = 4 * i - 32;
    if (base >= 0 && base + 64 < LEN) {
        // interior: 16 aligned float4 loads + 1 scalar (base byte offset % 16 == 0)
        #pragma unroll
        for (int q = 0; q < 16; q++) {
            float4 v = *reinterpret_cast<const float4*>(xb + base + 4 * q);
            w[4*q+0] = v.x; w[4*q+1] = v.y; w[4*q+2] = v.z; w[4*q+3] = v.w;
        }
        w[64] = xb[base + 64];
    } else {
        #pragma unroll
        for (int n = 0; n < NTAP; n++) {
            int p = base + n;
            w[n] = (p >= 0 && p < LEN) ? xb[p] : 0.f;
        }
    }
    float a0 = 0.f, a1 = 0.f, a2 = 0.f, a3 = 0.f;
    #pragma unroll
    for (int n = 0; n < NTAP; n++) {
        float v = w[n];
        a0 = fmaf(F.h[0][n], v, a0);
        a1 = fmaf(F.h[1][n], v, a1);
        a2 = fmaf(F.h[2][n], v, a2);
        a3 = fmaf(F.h[3][n], v, a3);
    }
    float* sb = sub + (size_t)b * (4 * LSUB) + i;
    sb[0 * LSUB] = a0;
    sb[1 * LSUB] = a1;
    sb[2 * LSUB] = a2;
    sb[3 * LSUB] = a3;
}

// ---- Synthesis: y[b,t] = sum_k sum_{n=4m+32-t in [0,64]} h[k][n] * sub[b,k,m] ----
// thread handles t = 4u..4u+3; with j = m-u+8 (j=0..16), n = 4j - p for phase p.
__global__ __launch_bounds__(256) void pqmf_synthesis(const float* __restrict__ sub,
                                                      float* __restrict__ y,
                                                      Filt F) {
    int idx = blockIdx.x * blockDim.x + threadIdx.x;   // BATCH*LSUB threads
    int u = idx & (LSUB - 1);
    int b = idx >> 17;
    const float* sb = sub + (size_t)b * (4 * LSUB);
    float a0 = 0.f, a1 = 0.f, a2 = 0.f, a3 = 0.f;
    bool interior = (u >= 8) && (u <= LSUB - 9);
    #pragma unroll
    for (int k = 0; k < 4; k++) {
        const float* sk = sb + k * LSUB;
        float sv[17];
        if (interior) {
            #pragma unroll
            for (int j = 0; j < 17; j++) sv[j] = sk[u - 8 + j];
        } else {
            #pragma unroll
            for (int j = 0; j < 17; j++) {
                int m = u - 8 + j;
                sv[j] = (m >= 0 && m < LSUB) ? sk[m] : 0.f;
            }
        }
        #pragma unroll
        for (int j = 0; j < 17; j++) a0 = fmaf(F.h[k][4 * j], sv[j], a0);
        #pragma unroll
        for (int j = 1; j < 17; j++) {
            a1 = fmaf(F.h[k][4 * j - 1], sv[j], a1);
            a2 = fmaf(F.h[k][4 * j - 2], sv[j], a2);
            a3 = fmaf(F.h[k][4 * j - 3], sv[j], a3);
        }
    }
    float4 out;
    out.x = a0; out.y = a1; out.z = a2; out.w = a3;
    *reinterpret_cast<float4*>(y + (size_t)b * LEN + 4 * (size_t)u) = out;
}

// ---------------- host ----------------
static double bessel_i0(double x) {
    double t = 1.0, s = 1.0;
    for (int m = 1; m < 80; m++) {
        double u = x / (2.0 * m);
        t *= u * u;
        s += t;
        if (t < s * 1e-18) break;
    }
    return s;
}

extern "C" void kernel_launch(void* const* d_in, const int* in_sizes, int n_in,
                              void* d_out, int out_size, void* d_ws, size_t ws_size,
                              hipStream_t stream) {
    const float* x = (const float*)d_in[0];
    float* y = (float*)d_out;
    float* sub = (float*)d_ws;   // needs BATCH*4*LSUB*4 = 33.55 MB

    // Recompute the deterministic QMF filter in double precision (matches
    // np.kaiser(65, 9.0)/sum * cos-modulation to ~1e-7, far below 2.5e-3 tol).
    Filt F;
    {
        double h[NTAP], sum = 0.0;
        double ib = bessel_i0(9.0);
        for (int n = 0; n < NTAP; n++) {
            double r = (n - 32.0) / 32.0;
            double arg = 1.0 - r * r;
            if (arg < 0.0) arg = 0.0;
            double v = bessel_i0(9.0 * sqrt(arg)) / ib;
            h[n] = v;
            sum += v;
        }
        for (int n = 0; n < NTAP; n++) h[n] /= sum;
        const double PI = 3.14159265358979323846;
        for (int k = 0; k < 4; k++)
            for (int n = 0; n < NTAP; n++) {
                double c = cos((2 * k + 1) * PI * n / 8.0 + ((k & 1) ? -1.0 : 1.0) * PI / 4.0);
                F.h[k][n] = (float)(h[n] * c);
            }
    }

    dim3 blk(256);
    dim3 grd((BATCH * LSUB) / 256);   // 8192 blocks
    pqmf_analysis<<<grd, blk, 0, stream>>>(x, sub, F);
    pqmf_synthesis<<<grd, blk, 0, stream>>>(sub, y, F);
}

// Round 2
// 125.037 us; speedup vs baseline: 1.0512x; 1.0512x over previous
//
#include <hip/hip_runtime.h>
#include <math.h>

#define NTAP 65
#define LEN 524288
#define LSUB 131072   // LEN/4
#define BATCH 16
#define TILE 256      // synthesis positions (u) per block
#define XS 1152       // staged x floats per block (covers 4*TILE + 2*64 window)
#define SROW 272      // sub positions per block (TILE + 16 halo)

struct Filt { float h[4][NTAP]; };   // 1040 B by value -> kernarg, scalar-cached

// compute the 4 subband outputs for one analysis position, window w[0..64]
__device__ __forceinline__ float4 analyze(const float* __restrict__ w, const Filt& F) {
    float a[4] = {0.f, 0.f, 0.f, 0.f};
    #pragma unroll
    for (int q = 0; q < 16; q++) {
        float4 v = *reinterpret_cast<const float4*>(w + 4 * q);
        #pragma unroll
        for (int k = 0; k < 4; k++) {
            a[k] = fmaf(F.h[k][4 * q + 0], v.x, a[k]);
            a[k] = fmaf(F.h[k][4 * q + 1], v.y, a[k]);
            a[k] = fmaf(F.h[k][4 * q + 2], v.z, a[k]);
            a[k] = fmaf(F.h[k][4 * q + 3], v.w, a[k]);
        }
    }
    float vx = w[64];
    #pragma unroll
    for (int k = 0; k < 4; k++) a[k] = fmaf(F.h[k][64], vx, a[k]);
    return make_float4(a[0], a[1], a[2], a[3]);
}

__global__ __launch_bounds__(256) void pqmf_fused(const float* __restrict__ x,
                                                  float* __restrict__ y,
                                                  Filt F) {
    __shared__ float xs[XS];
    __shared__ float4 subs[SROW];   // [pos][subband] interleaved -> b128 LDS ops

    const int t = threadIdx.x;
    const int b = blockIdx.x >> 9;           // 512 tiles per batch row
    const int u0 = (blockIdx.x & 511) << 8;  // tile * TILE
    const float* xb = x + (size_t)b * LEN;
    const int xbase = 4 * u0 - 64;           // x index of xs[0]

    // ---- stage x tile into LDS ----
    if (xbase >= 0 && xbase + XS <= LEN) {
        *reinterpret_cast<float4*>(&xs[4 * t]) =
            *reinterpret_cast<const float4*>(xb + xbase + 4 * t);
        if (t < (XS - 4 * TILE) / 4) {
            *reinterpret_cast<float4*>(&xs[4 * TILE + 4 * t]) =
                *reinterpret_cast<const float4*>(xb + xbase + 4 * TILE + 4 * t);
        }
    } else {
        // edge blocks: per-element zero-padded staging
        for (int q = t; q < XS / 4; q += 256) {
            float v[4];
            #pragma unroll
            for (int c = 0; c < 4; c++) {
                int p = xbase + 4 * q + c;
                v[c] = (p >= 0 && p < LEN) ? xb[p] : 0.f;
            }
            float4 vv; vv.x = v[0]; vv.y = v[1]; vv.z = v[2]; vv.w = v[3];
            *reinterpret_cast<float4*>(&xs[4 * q]) = vv;
        }
    }
    __syncthreads();

    // ---- analysis: sub[i] for i = u0-8 .. u0+263 ----
    {
        // pass 1: all threads, position index t  (i = u0-8+t), window = xs[4t .. 4t+64]
        float4 s = analyze(&xs[4 * t], F);
        int i = u0 - 8 + t;
        bool valid = (i >= 0) && (i < LSUB);
        if (!valid) s = make_float4(0.f, 0.f, 0.f, 0.f);
        subs[t] = s;
    }
    if (t < SROW - TILE) {
        // pass 2: halo positions 256..271 (one exec-mask group; waves 1-3 skip)
        float4 s = analyze(&xs[4 * (TILE + t)], F);
        int i = u0 - 8 + TILE + t;
        bool valid = (i >= 0) && (i < LSUB);
        if (!valid) s = make_float4(0.f, 0.f, 0.f, 0.f);
        subs[TILE + t] = s;
    }
    __syncthreads();

    // ---- synthesis: y[4u + p], u = u0 + t, p = 0..3 ----
    float a0 = 0.f, a1 = 0.f, a2 = 0.f, a3 = 0.f;
    {
        float4 v = subs[t];   // j = 0, n = 0 contributes to phase 0 only
        a0 = fmaf(F.h[0][0], v.x, a0);
        a0 = fmaf(F.h[1][0], v.y, a0);
        a0 = fmaf(F.h[2][0], v.z, a0);
        a0 = fmaf(F.h[3][0], v.w, a0);
    }
    #pragma unroll
    for (int j = 1; j <= 16; j++) {
        float4 v = subs[t + j];
        a0 = fmaf(F.h[0][4 * j], v.x, a0);
        a0 = fmaf(F.h[1][4 * j], v.y, a0);
        a0 = fmaf(F.h[2][4 * j], v.z, a0);
        a0 = fmaf(F.h[3][4 * j], v.w, a0);
        a1 = fmaf(F.h[0][4 * j - 1], v.x, a1);
        a1 = fmaf(F.h[1][4 * j - 1], v.y, a1);
        a1 = fmaf(F.h[2][4 * j - 1], v.z, a1);
        a1 = fmaf(F.h[3][4 * j - 1], v.w, a1);
        a2 = fmaf(F.h[0][4 * j - 2], v.x, a2);
        a2 = fmaf(F.h[1][4 * j - 2], v.y, a2);
        a2 = fmaf(F.h[2][4 * j - 2], v.z, a2);
        a2 = fmaf(F.h[3][4 * j - 2], v.w, a2);
        a3 = fmaf(F.h[0][4 * j - 3], v.x, a3);
        a3 = fmaf(F.h[1][4 * j - 3], v.y, a3);
        a3 = fmaf(F.h[2][4 * j - 3], v.z, a3);
        a3 = fmaf(F.h[3][4 * j - 3], v.w, a3);
    }
    float4 o; o.x = a0; o.y = a1; o.z = a2; o.w = a3;
    *reinterpret_cast<float4*>(y + (size_t)b * LEN + 4 * (size_t)(u0 + t)) = o;
}

// ---------------- host ----------------
static double bessel_i0(double x) {
    double t = 1.0, s = 1.0;
    for (int m = 1; m < 80; m++) {
        double u = x / (2.0 * m);
        t *= u * u;
        s += t;
        if (t < s * 1e-18) break;
    }
    return s;
}

extern "C" void kernel_launch(void* const* d_in, const int* in_sizes, int n_in,
                              void* d_out, int out_size, void* d_ws, size_t ws_size,
                              hipStream_t stream) {
    const float* x = (const float*)d_in[0];
    float* y = (float*)d_out;

    // Recompute the deterministic QMF filter in double precision (matches
    // np.kaiser(65, 9.0)/sum * cos-modulation to ~1e-7, far below 2.5e-3 tol).
    Filt F;
    {
        double h[NTAP], sum = 0.0;
        double ib = bessel_i0(9.0);
        for (int n = 0; n < NTAP; n++) {
            double r = (n - 32.0) / 32.0;
            double arg = 1.0 - r * r;
            if (arg < 0.0) arg = 0.0;
            double v = bessel_i0(9.0 * sqrt(arg)) / ib;
            h[n] = v;
            sum += v;
        }
        for (int n = 0; n < NTAP; n++) h[n] /= sum;
        const double PI = 3.14159265358979323846;
        for (int k = 0; k < 4; k++)
            for (int n = 0; n < NTAP; n++) {
                double c = cos((2 * k + 1) * PI * n / 8.0 + ((k & 1) ? -1.0 : 1.0) * PI / 4.0);
                F.h[k][n] = (float)(h[n] * c);
            }
    }

    dim3 blk(256);
    dim3 grd(BATCH * (LSUB / TILE));   // 16 * 512 = 8192 blocks
    pqmf_fused<<<grd, blk, 0, stream>>>(x, y, F);
}

// Round 3
// 105.936 us; speedup vs baseline: 1.2407x; 1.1803x over previous
//
#include <hip/hip_runtime.h>
#include <math.h>

#define NTAP 65
#define LEN 524288
#define LSUB 131072
#define BATCH 16
#define UT 1024      // synthesis positions (u) per block
#define NSUB 1040    // UT + 16 halo analysis positions
#define NXG 1056     // staged x float4-granules per block

struct Filt2 { float f0[NTAP]; float f1[NTAP]; };  // k=0,1 filters; k=2,3 by symmetry

// XOR swizzle on float4-granule index: conflict-free for both the contiguous
// staging pattern (g = t) and the strided compute pattern (g = 4t + j).
__device__ __forceinline__ int swz(int g) { return g ^ ((g >> 3) & 7); }

// Analysis of 4 consecutive positions s0..s0+3 (s is block-local sub index,
// global position i = u0 - 8 + s). Window = xs granules [s0, s0+20).
__device__ __forceinline__ void analyze4(const float4* __restrict__ xs, int s0, int u0,
                                         const Filt2& F, float4* __restrict__ subs) {
    float w[80];
    #pragma unroll
    for (int j = 0; j < 20; j++) {
        float4 v = xs[swz(s0 + j)];
        w[4*j+0] = v.x; w[4*j+1] = v.y; w[4*j+2] = v.z; w[4*j+3] = v.w;
    }
    #pragma unroll
    for (int c = 0; c < 4; c++) {
        float e0 = 0.f, o0 = 0.f, e1 = 0.f, o1 = 0.f;
        #pragma unroll
        for (int n = 0; n < NTAP; n++) {
            float v = w[4*c + n];
            if (n & 1) { o0 = fmaf(F.f0[n], v, o0); o1 = fmaf(F.f1[n], v, o1); }
            else       { e0 = fmaf(F.f0[n], v, e0); e1 = fmaf(F.f1[n], v, e1); }
        }
        int i = u0 - 8 + s0 + c;
        float4 r = make_float4(e0 + o0, e1 + o1, e1 - o1, e0 - o0);  // k=0..3
        if (i < 0 || i >= LSUB) r = make_float4(0.f, 0.f, 0.f, 0.f);
        subs[swz(s0 + c)] = r;
    }
}

__global__ __launch_bounds__(256, 4) void pqmf_fused(const float* __restrict__ x,
                                                     float* __restrict__ y, Filt2 F) {
    __shared__ float4 xs[NXG];     // x[4*u0-64 ...], 16.9 KB
    __shared__ float4 subs[NSUB];  // sub[u0-8 .. u0+1031], [pos][k], 16.6 KB

    const int t = threadIdx.x;
    const int b = blockIdx.x >> 7;            // 128 tiles per batch row
    const int u0 = (blockIdx.x & 127) << 10;  // tile * UT
    const float* xb = x + (size_t)b * LEN;
    const int gbase = u0 - 16;                // global granule index of xs[0]

    // ---- stage x tile (coalesced float4, swizzled LDS dest) ----
    if (gbase >= 0 && gbase + NXG <= LEN / 4) {
        #pragma unroll
        for (int p = 0; p < 4; p++)
            xs[swz(t + 256 * p)] = *reinterpret_cast<const float4*>(xb + 4 * (gbase + t + 256 * p));
        if (t < NXG - 1024)
            xs[swz(t + 1024)] = *reinterpret_cast<const float4*>(xb + 4 * (gbase + t + 1024));
    } else {
        for (int r = t; r < NXG; r += 256) {
            int g = gbase + r;
            float v[4];
            #pragma unroll
            for (int c2 = 0; c2 < 4; c2++) {
                int p = 4 * g + c2;
                v[c2] = (p >= 0 && p < LEN) ? xb[p] : 0.f;
            }
            xs[swz(r)] = make_float4(v[0], v[1], v[2], v[3]);
        }
    }
    __syncthreads();

    // ---- analysis: 1024 positions via all threads + 16 halo (1 group per wave) ----
    analyze4(xs, 4 * t, u0, F, subs);
    if ((t & 63) == 0) analyze4(xs, UT + 4 * (t >> 6), u0, F, subs);
    __syncthreads();

    // ---- synthesis: u = u0 + 4t + c, c = 0..3 ----
    float P[20], M[20], Q[20], R[20];
    #pragma unroll
    for (int j = 0; j < 20; j++) {
        float4 v = subs[swz(4 * t + j)];
        P[j] = v.x + v.w; M[j] = v.x - v.w;   // k0 +/- k3
        Q[j] = v.y + v.z; R[j] = v.y - v.z;   // k1 +/- k2
    }
    float* yb = y + (size_t)b * LEN;
    #pragma unroll
    for (int c = 0; c < 4; c++) {
        float a0 = 0.f, a1 = 0.f, a2 = 0.f, a3 = 0.f;
        #pragma unroll
        for (int j2 = 0; j2 <= 16; j2++) {       // phase 0: taps n = 4*j2 (even)
            a0 = fmaf(F.f0[4 * j2], P[c + j2], a0);
            a0 = fmaf(F.f1[4 * j2], Q[c + j2], a0);
        }
        #pragma unroll
        for (int j2 = 1; j2 <= 16; j2++) {       // phases 1..3
            a1 = fmaf(F.f0[4 * j2 - 1], M[c + j2], a1);  // n odd
            a1 = fmaf(F.f1[4 * j2 - 1], R[c + j2], a1);
            a2 = fmaf(F.f0[4 * j2 - 2], P[c + j2], a2);  // n even
            a2 = fmaf(F.f1[4 * j2 - 2], Q[c + j2], a2);
            a3 = fmaf(F.f0[4 * j2 - 3], M[c + j2], a3);  // n odd
            a3 = fmaf(F.f1[4 * j2 - 3], R[c + j2], a3);
        }
        *reinterpret_cast<float4*>(yb + 4 * (size_t)(u0 + 4 * t + c)) =
            make_float4(a0, a1, a2, a3);
    }
}

// ---------------- host ----------------
static double bessel_i0(double x) {
    double t = 1.0, s = 1.0;
    for (int m = 1; m < 80; m++) {
        double u = x / (2.0 * m);
        t *= u * u;
        s += t;
        if (t < s * 1e-18) break;
    }
    return s;
}

extern "C" void kernel_launch(void* const* d_in, const int* in_sizes, int n_in,
                              void* d_out, int out_size, void* d_ws, size_t ws_size,
                              hipStream_t stream) {
    const float* x = (const float*)d_in[0];
    float* y = (float*)d_out;

    // Deterministic QMF filter recomputed in double precision (matches numpy
    // np.kaiser(65, 9.0)/sum * cos-modulation to ~1e-7 << 2.5e-3 tolerance).
    // Only k=0,1 needed: filt[3-k][n] = (-1)^n * filt[k][n].
    Filt2 F;
    {
        double h[NTAP], sum = 0.0;
        double ib = bessel_i0(9.0);
        for (int n = 0; n < NTAP; n++) {
            double r = (n - 32.0) / 32.0;
            double arg = 1.0 - r * r;
            if (arg < 0.0) arg = 0.0;
            h[n] = bessel_i0(9.0 * sqrt(arg)) / ib;
            sum += h[n];
        }
        for (int n = 0; n < NTAP; n++) h[n] /= sum;
        const double PI = 3.14159265358979323846;
        for (int n = 0; n < NTAP; n++) {
            F.f0[n] = (float)(h[n] * cos(1.0 * PI * n / 8.0 + PI / 4.0));
            F.f1[n] = (float)(h[n] * cos(3.0 * PI * n / 8.0 - PI / 4.0));
        }
    }

    dim3 blk(256);
    dim3 grd(BATCH * (LSUB / UT));   // 16 * 128 = 2048 blocks (8 per CU)
    pqmf_fused<<<grd, blk, 0, stream>>>(x, y, F);
}

// Round 4
// 97.919 us; speedup vs baseline: 1.3423x; 1.0819x over previous
//
#include <hip/hip_runtime.h>
#include <math.h>

#define NTAP 65
#define LEN 524288
#define LSUB 131072
#define BATCH 16
#define UT 1024      // synthesis positions (u) per block
#define NSUB 1040    // UT + 16 halo analysis positions (8*130)
#define NXG 1056     // staged x float4-granules per block (8*132)

struct Filt2 { float f0[NTAP]; float f1[NTAP]; };  // k=0,1; k=2,3 by (-1)^n symmetry

// XOR swizzle on float4-granule index: conflict-free (2-way, free) for both the
// contiguous pattern (g = t + 256p) and the strided pattern (g = 4t + j).
__device__ __forceinline__ int swz(int g) { return g ^ ((g >> 3) & 7); }

__global__ __launch_bounds__(256, 4) void pqmf_fused(const float* __restrict__ x,
                                                     float* __restrict__ y, Filt2 F) {
    __shared__ float4 xs[NXG];     // x granules gbase.. (16.9 KB)
    __shared__ float4 subs[NSUB];  // sub[u0-8 .. u0+1031] as [pos][k] (16.6 KB)

    const int t = threadIdx.x;
    const int b = blockIdx.x >> 7;            // 128 tiles per batch row
    const int u0 = (blockIdx.x & 127) << 10;  // tile * UT
    const float* xb = x + (size_t)b * LEN;
    const int gbase = u0 - 16;                // global x-granule index of xs[0]

    // ---- stage x tile (coalesced float4, swizzled LDS dest) ----
    if (gbase >= 0 && gbase + NXG <= LEN / 4) {
        #pragma unroll
        for (int p = 0; p < 4; p++)
            xs[swz(t + 256 * p)] = *reinterpret_cast<const float4*>(xb + 4 * (gbase + t + 256 * p));
        if (t < NXG - 1024)
            xs[swz(t + 1024)] = *reinterpret_cast<const float4*>(xb + 4 * (gbase + t + 1024));
    } else {
        for (int r = t; r < NXG; r += 256) {
            int g = gbase + r;
            float v[4];
            #pragma unroll
            for (int c2 = 0; c2 < 4; c2++) {
                int p = 4 * g + c2;
                v[c2] = (p >= 0 && p < LEN) ? xb[p] : 0.f;
            }
            xs[swz(r)] = make_float4(v[0], v[1], v[2], v[3]);
        }
    }
    __syncthreads();

    // ---- analysis, streaming: positions s = 4t..4t+3 (i = u0-8+s) ----
    {
        float e0[4] = {0.f,0.f,0.f,0.f}, o0[4] = {0.f,0.f,0.f,0.f};
        float e1[4] = {0.f,0.f,0.f,0.f}, o1[4] = {0.f,0.f,0.f,0.f};
        #pragma unroll
        for (int j = 0; j < 20; j++) {
            float4 v = xs[swz(4 * t + j)];
            #pragma unroll
            for (int c = 0; c < 4; c++) {
                int d = j - c;                 // granule offset within window
                if (d == 16) {                 // tap n = 64 (even), x component only
                    e0[c] = fmaf(F.f0[64], v.x, e0[c]);
                    e1[c] = fmaf(F.f1[64], v.x, e1[c]);
                } else if (d >= 0 && d < 16) { // taps n = 4d .. 4d+3
                    int n = 4 * d;
                    e0[c] = fmaf(F.f0[n    ], v.x, e0[c]);
                    o0[c] = fmaf(F.f0[n + 1], v.y, o0[c]);
                    e0[c] = fmaf(F.f0[n + 2], v.z, e0[c]);
                    o0[c] = fmaf(F.f0[n + 3], v.w, o0[c]);
                    e1[c] = fmaf(F.f1[n    ], v.x, e1[c]);
                    o1[c] = fmaf(F.f1[n + 1], v.y, o1[c]);
                    e1[c] = fmaf(F.f1[n + 2], v.z, e1[c]);
                    o1[c] = fmaf(F.f1[n + 3], v.w, o1[c]);
                }
            }
        }
        #pragma unroll
        for (int c = 0; c < 4; c++) {
            int s = 4 * t + c;
            int i = u0 - 8 + s;
            float4 r = make_float4(e0[c] + o0[c], e1[c] + o1[c],
                                   e1[c] - o1[c], e0[c] - o0[c]);   // k = 0..3
            if (i < 0 || i >= LSUB) r = make_float4(0.f, 0.f, 0.f, 0.f);
            subs[swz(s)] = r;
        }
    }
    // halo positions s = 1024..1039: threads 0..15 only (wave 0), one position each
    if (t < 16) {
        int s = UT + t;
        float E0 = 0.f, O0 = 0.f, E1 = 0.f, O1 = 0.f;
        #pragma unroll
        for (int j = 0; j <= 16; j++) {
            float4 v = xs[swz(s + j)];
            if (j == 16) {
                E0 = fmaf(F.f0[64], v.x, E0);
                E1 = fmaf(F.f1[64], v.x, E1);
            } else {
                int n = 4 * j;
                E0 = fmaf(F.f0[n    ], v.x, E0);
                O0 = fmaf(F.f0[n + 1], v.y, O0);
                E0 = fmaf(F.f0[n + 2], v.z, E0);
                O0 = fmaf(F.f0[n + 3], v.w, O0);
                E1 = fmaf(F.f1[n    ], v.x, E1);
                O1 = fmaf(F.f1[n + 1], v.y, O1);
                E1 = fmaf(F.f1[n + 2], v.z, E1);
                O1 = fmaf(F.f1[n + 3], v.w, O1);
            }
        }
        int i = u0 - 8 + s;
        float4 r = make_float4(E0 + O0, E1 + O1, E1 - O1, E0 - O0);
        if (i < 0 || i >= LSUB) r = make_float4(0.f, 0.f, 0.f, 0.f);
        subs[swz(s)] = r;
    }
    __syncthreads();

    // ---- synthesis, streaming: outputs u = u0 + 4t + c ----
    {
        float a0[4] = {0.f,0.f,0.f,0.f}, a1[4] = {0.f,0.f,0.f,0.f};
        float a2[4] = {0.f,0.f,0.f,0.f}, a3[4] = {0.f,0.f,0.f,0.f};
        #pragma unroll
        for (int j = 0; j < 20; j++) {
            float4 v = subs[swz(4 * t + j)];
            float p = v.x + v.w, m = v.x - v.w;   // k0 +/- k3  (n even / n odd)
            float q = v.y + v.z, r = v.y - v.z;   // k1 +/- k2
            #pragma unroll
            for (int c = 0; c < 4; c++) {
                int j2 = j - c;
                if (j2 >= 0 && j2 <= 16) {
                    a0[c] = fmaf(F.f0[4 * j2], p, a0[c]);       // n = 4j2 (even)
                    a0[c] = fmaf(F.f1[4 * j2], q, a0[c]);
                    if (j2 >= 1) {
                        a1[c] = fmaf(F.f0[4 * j2 - 1], m, a1[c]);  // n odd
                        a1[c] = fmaf(F.f1[4 * j2 - 1], r, a1[c]);
                        a2[c] = fmaf(F.f0[4 * j2 - 2], p, a2[c]);  // n even
                        a2[c] = fmaf(F.f1[4 * j2 - 2], q, a2[c]);
                        a3[c] = fmaf(F.f0[4 * j2 - 3], m, a3[c]);  // n odd
                        a3[c] = fmaf(F.f1[4 * j2 - 3], r, a3[c]);
                    }
                }
            }
        }
        float* yb = y + (size_t)b * LEN;
        #pragma unroll
        for (int c = 0; c < 4; c++)
            *reinterpret_cast<float4*>(yb + 4 * (size_t)(u0 + 4 * t + c)) =
                make_float4(a0[c], a1[c], a2[c], a3[c]);
    }
}

// ---------------- host ----------------
static double bessel_i0(double x) {
    double t = 1.0, s = 1.0;
    for (int m = 1; m < 80; m++) {
        double u = x / (2.0 * m);
        t *= u * u;
        s += t;
        if (t < s * 1e-18) break;
    }
    return s;
}

extern "C" void kernel_launch(void* const* d_in, const int* in_sizes, int n_in,
                              void* d_out, int out_size, void* d_ws, size_t ws_size,
                              hipStream_t stream) {
    const float* x = (const float*)d_in[0];
    float* y = (float*)d_out;

    // Deterministic QMF filter recomputed in double precision (matches numpy
    // np.kaiser(65, 9.0)/sum * cos-modulation to ~1e-7 << 2.5e-3 tolerance).
    // Only k=0,1 needed: filt[3-k][n] = (-1)^n * filt[k][n].
    Filt2 F;
    {
        double h[NTAP], sum = 0.0;
        double ib = bessel_i0(9.0);
        for (int n = 0; n < NTAP; n++) {
            double r = (n - 32.0) / 32.0;
            double arg = 1.0 - r * r;
            if (arg < 0.0) arg = 0.0;
            h[n] = bessel_i0(9.0 * sqrt(arg)) / ib;
            sum += h[n];
        }
        for (int n = 0; n < NTAP; n++) h[n] /= sum;
        const double PI = 3.14159265358979323846;
        for (int n = 0; n < NTAP; n++) {
            F.f0[n] = (float)(h[n] * cos(1.0 * PI * n / 8.0 + PI / 4.0));
            F.f1[n] = (float)(h[n] * cos(3.0 * PI * n / 8.0 - PI / 4.0));
        }
    }

    dim3 blk(256);
    dim3 grd(BATCH * (LSUB / UT));   // 16 * 128 = 2048 blocks
    pqmf_fused<<<grd, blk, 0, stream>>>(x, y, F);
}